// Round 7
// baseline (29.055 us; speedup 1.0000x reference)
//
#include <hip/hip_runtime.h>

// out[b,k] = tanh( sum_{m in segment k} x[b,m] * w[m] ),  seg_ids sorted.
//
// R7: prefix-sum segmented reduction.
//  K1: O(M) boundary scatter -> seg_ptr (CSR), coalesced, ~2us.
//  K2: block = 1 wave, 64 segments x NB=2 batches.
//    - lane ln owns 20 CONTIGUOUS window positions [ln*20, ln*20+20)
//    - load 5 float4 of w + 5 per batch of x (all issued back-to-back,
//      index clamped to M/4-1 -> no guards, garbage only lands >= e)
//    - products -> running local prefix (20 fmac) -> 6-step wave scan ->
//      inclusive global prefix written to LDS (5 ds_write_b128)
//    - segment sum = I[hi-1] - I[lo-1]: 2 LDS reads + 1 sub per output.
//      Uniform control flow, no per-element masking (R5/R6's VALU floor).
// Rationale: R5 counters showed VALU (masked reduce) + search latency chain
// were the cost, not HBM and not occupancy.

#define SEGB 64               // segments per block (= lanes)
#define NB   2                // batches per block
#define TPB  64               // one wave
#define LPT  20               // floats per lane = CH/64
#define CH   (64 * LPT)       // 1280-float window (mean 1024 + 8 sigma)
#define F4L  (LPT / 4)        // float4 loads per lane per stream = 5

__global__ void build_seg_ptr_scatter(const int* __restrict__ seg_ids,
                                      int* __restrict__ seg_ptr,
                                      int M, int K) {
    int m = blockIdx.x * blockDim.x + threadIdx.x;
    if (m >= M) return;
    int a  = seg_ids[m];
    int nb = (m + 1 < M) ? seg_ids[m + 1] : K;
    if (m == 0) {
        for (int k = 0; k <= a; ++k) seg_ptr[k] = 0;
    }
    for (int k = a + 1; k <= nb; ++k) seg_ptr[k] = m + 1;
}

__global__ __launch_bounds__(TPB) void seg_prefix_tanh(
        const float* __restrict__ x,
        const float* __restrict__ w,
        const int* __restrict__ sp,
        float* __restrict__ out,
        int M, int K) {
    __shared__ __align__(16) float I[NB][CH];

    const int ln = threadIdx.x;           // lane
    const int k0 = blockIdx.x * SEGB;
    const int b0 = blockIdx.y * NB;
    const int M4 = M >> 2;

    const int s   = sp[k0];               // block-uniform -> s_load
    const int e   = sp[k0 + SEGB];        // block-uniform
    const int a_t = sp[k0 + ln];          // lane's segment [a_t, b_t)
    const int b_t = sp[k0 + ln + 1];
    const int base = s & ~3;              // 16B-aligned window start

    const float4* __restrict__ w4 = reinterpret_cast<const float4*>(w);
    const float4* __restrict__ x4a = reinterpret_cast<const float4*>(x + (size_t)(b0 + 0) * M);
    const float4* __restrict__ x4b = reinterpret_cast<const float4*>(x + (size_t)(b0 + 1) * M);

    float sum0 = 0.0f, sum1 = 0.0f;

    for (int c = base; c < e; c += CH) {  // single trip in practice
        const int f40 = (c >> 2) + ln * F4L;
        float4 wq[F4L], xqa[F4L], xqb[F4L];
        // ---- all 15 loads issued unconditionally, back-to-back ----
        #pragma unroll
        for (int j = 0; j < F4L; ++j) {
            int f4 = min(f40 + j, M4 - 1);    // clamp: garbage lands >= e only
            wq[j]  = w4[f4];
            xqa[j] = x4a[f4];
            xqb[j] = x4b[f4];
        }
        // ---- per batch: local prefix -> wave scan -> LDS inclusive prefix ----
        #pragma unroll
        for (int bb = 0; bb < NB; ++bb) {
            float L[LPT];
            float run = 0.0f;
            #pragma unroll
            for (int j = 0; j < F4L; ++j) {
                float4 xv = (bb == 0) ? xqa[j] : xqb[j];
                run = fmaf(xv.x, wq[j].x, run); L[j*4+0] = run;
                run = fmaf(xv.y, wq[j].y, run); L[j*4+1] = run;
                run = fmaf(xv.z, wq[j].z, run); L[j*4+2] = run;
                run = fmaf(xv.w, wq[j].w, run); L[j*4+3] = run;
            }
            float S = run;                    // inclusive wave scan of lane totals
            #pragma unroll
            for (int d = 1; d < 64; d <<= 1) {
                float u = __shfl_up(S, d);
                if (ln >= d) S += u;
            }
            const float E = S - run;          // exclusive prefix of this lane
            float4* Ip4 = reinterpret_cast<float4*>(&I[bb][ln * LPT]);
            #pragma unroll
            for (int j = 0; j < F4L; ++j) {
                Ip4[j] = make_float4(L[j*4+0] + E, L[j*4+1] + E,
                                     L[j*4+2] + E, L[j*4+3] + E);
            }
        }
        __syncthreads();                      // 1-wave block: lgkm drain only
        // ---- segment sum = prefix difference (2 reads + 1 sub) ----
        {
            int lo = max(a_t, c) - c;
            int hi = min(b_t, c + CH) - c;
            if (hi > lo) {
                float ph0 = I[0][hi - 1];
                float pl0 = (lo > 0) ? I[0][lo - 1] : 0.0f;
                float ph1 = I[1][hi - 1];
                float pl1 = (lo > 0) ? I[1][lo - 1] : 0.0f;
                sum0 += ph0 - pl0;
                sum1 += ph1 - pl1;
            }
        }
        __syncthreads();                      // protect I before next chunk
    }

    out[(size_t)(b0 + 0) * K + k0 + ln] = tanhf(sum0);
    out[(size_t)(b0 + 1) * K + k0 + ln] = tanhf(sum1);
}

extern "C" void kernel_launch(void* const* d_in, const int* in_sizes, int n_in,
                              void* d_out, int out_size, void* d_ws, size_t ws_size,
                              hipStream_t stream) {
    const float* x       = (const float*)d_in[0];
    const float* w       = (const float*)d_in[1];
    const int*   seg_ids = (const int*)d_in[2];
    float* out = (float*)d_out;

    const int M = in_sizes[1];           // 65536 (w length)
    const int B = in_sizes[0] / M;       // 256
    const int K = out_size / B;          // 4096

    int* seg_ptr = (int*)d_ws;           // K+1 ints in workspace

    build_seg_ptr_scatter<<<(M + 255) / 256, 256, 0, stream>>>(seg_ids, seg_ptr, M, K);

    dim3 grid(K / SEGB, B / NB);         // (64, 128) = 8192 blocks
    seg_prefix_tanh<<<grid, TPB, 0, stream>>>(x, w, seg_ptr, out, M, K);
}